// Round 7
// baseline (68.562 us; speedup 1.0000x reference)
//
#include <hip/hip_runtime.h>

#define S 512
#define Dm 512

typedef __bf16 bf16x8 __attribute__((ext_vector_type(8)));
typedef float f32x4 __attribute__((ext_vector_type(4)));

// ---------------- prep: hs->bf16 (blocks 0..127) ; W->WT bf16 (blocks 128..383) ----------------
__global__ __launch_bounds__(256) void prep_kernel(
    const float* __restrict__ hs,
    const float* __restrict__ W0, const float* __restrict__ W1,
    const float* __restrict__ W2, const float* __restrict__ W3,
    __bf16* __restrict__ Abf,
    __bf16* __restrict__ T0, __bf16* __restrict__ T1,
    __bf16* __restrict__ T2, __bf16* __restrict__ T3)
{
    __shared__ __bf16 Tl[64][72];
    int u = threadIdx.x;
    if (blockIdx.x < 128) {
        int i = (blockIdx.x * 256 + u) * 8;
        float4 x0 = *(const float4*)(hs + i);
        float4 x1 = *(const float4*)(hs + i + 4);
        bf16x8 y;
        y[0] = (__bf16)x0.x; y[1] = (__bf16)x0.y; y[2] = (__bf16)x0.z; y[3] = (__bf16)x0.w;
        y[4] = (__bf16)x1.x; y[5] = (__bf16)x1.y; y[6] = (__bf16)x1.z; y[7] = (__bf16)x1.w;
        *(bf16x8*)(Abf + i) = y;
        return;
    }
    int blk = blockIdx.x - 128;
    int m = blk >> 6;
    int t = blk & 63;
    const float* W = (m == 0) ? W0 : (m == 1) ? W1 : (m == 2) ? W2 : W3;
    __bf16* T = (m == 0) ? T0 : (m == 1) ? T1 : (m == 2) ? T2 : T3;
    int k0 = (t >> 3) << 6;
    int n0 = (t & 7) << 6;
    {
        int kk = u >> 4;
        int n4 = (u & 15) << 2;
        #pragma unroll
        for (int p = 0; p < 4; ++p) {
            int k = kk + (p << 4);
            float4 wv = *(const float4*)(W + (k0 + k) * Dm + n0 + n4);
            Tl[n4 + 0][k] = (__bf16)wv.x;
            Tl[n4 + 1][k] = (__bf16)wv.y;
            Tl[n4 + 2][k] = (__bf16)wv.z;
            Tl[n4 + 3][k] = (__bf16)wv.w;
        }
    }
    __syncthreads();
    {
        int n = u >> 2;
        int ks = (u & 3) << 4;
        uint4 d0 = *(const uint4*)&Tl[n][ks];
        uint4 d1 = *(const uint4*)&Tl[n][ks + 8];
        *(uint4*)(T + (n0 + n) * Dm + k0 + ks) = d0;
        *(uint4*)(T + (n0 + n) * Dm + k0 + ks + 8) = d1;
    }
}

// ---------------- bf16 MFMA GEMM, latency-optimized: 32x32 tile, 2x2 waves of 16x16 ----------------
// grid = nmat*256 blocks, 256 thr. tile = blk&255 -> rt=tile>>4, ct=tile&15.
// wave w: (wr=w>>1, wc=w&1); per-wave out 16x16; 1 MFMA + 2 b128 loads per k-step.
__global__ __launch_bounds__(256) void mfma_gemm3(
    const __bf16* __restrict__ Abf,
    const __bf16* __restrict__ T0, const __bf16* __restrict__ T1, const __bf16* __restrict__ T2,
    const float* __restrict__ b0, const float* __restrict__ b1, const float* __restrict__ b2,
    float* __restrict__ O0, float* __restrict__ O1, float* __restrict__ O2)
{
    int blk = blockIdx.x;
    int m = blk >> 8;
    int tile = blk & 255;
    const __bf16* T = (m == 0) ? T0 : (m == 1) ? T1 : T2;
    const float* bias = (m == 0) ? b0 : (m == 1) ? b1 : b2;
    float* O = (m == 0) ? O0 : (m == 1) ? O1 : O2;
    int rt = tile >> 4, ct = tile & 15;

    int u = threadIdx.x;
    int w = u >> 6, lane = u & 63;
    int r = lane & 15, kg = lane >> 4;

    int row0 = (rt << 5) + ((w >> 1) << 4);
    int col0 = (ct << 5) + ((w & 1) << 4);

    const __bf16* Ap = Abf + (row0 + r) * Dm + (kg << 3);
    const __bf16* Bp = T + (col0 + r) * Dm + (kg << 3);

    f32x4 acc = {0.f, 0.f, 0.f, 0.f};

    #pragma unroll 4
    for (int k0 = 0; k0 < Dm; k0 += 32) {
        bf16x8 a = *(const bf16x8*)(Ap + k0);
        bf16x8 b = *(const bf16x8*)(Bp + k0);
        acc = __builtin_amdgcn_mfma_f32_16x16x32_bf16(a, b, acc, 0, 0, 0);
    }

    int orow = row0 + (kg << 2);
    float bb = bias[col0 + r];
    #pragma unroll
    for (int t = 0; t < 4; ++t)
        O[(orow + t) * Dm + col0 + r] = acc[t] + bb;
}

// ---------------- z-pass: lane = i, Q-row in VGPRs, K via wave-uniform loads ----------------
// grid 1024 = 8 heads * 8 i-tiles(64) * 16 j-tiles(32). 512 thr = 8 waves; wave w: 4 j's.
__global__ __launch_bounds__(512) void zfast_kernel(
    const float* __restrict__ Q, const float* __restrict__ K,
    const float* __restrict__ mask, const float* __restrict__ gamma,
    const float* __restrict__ alpha,
    float* __restrict__ zp, float* __restrict__ Zpart)
{
    int blk = blockIdx.x;
    int h  = blk >> 7;
    int it = (blk >> 4) & 7;
    int jt = blk & 15;
    int i0 = it << 6;
    int j0 = jt << 5;
    int c0 = h << 6;

    int u = threadIdx.x;
    int w = u >> 6, lane = u & 63;

    __shared__ float zsT[32][65];      // [j][i] transpose buffer
    __shared__ float partial[8][64];

    // per-lane Q row (row i0+lane), 64 VGPRs, static indexing
    float qreg[64];
    #pragma unroll
    for (int t = 0; t < 16; ++t) {
        float4 qv = *(const float4*)(Q + (i0 + lane) * Dm + c0 + (t << 2));
        qreg[4 * t + 0] = qv.x; qreg[4 * t + 1] = qv.y;
        qreg[4 * t + 2] = qv.z; qreg[4 * t + 3] = qv.w;
    }

    float sc = 1.0f / (gamma[0] * 8.0f);
    float al = alpha[0];

    int jb = __builtin_amdgcn_readfirstlane(w << 2);

    float zsum = 0.f;
    #pragma unroll 2
    for (int jj = 0; jj < 4; ++jj) {
        const float* kr = K + (j0 + jb + jj) * Dm + c0;   // uniform pointer
        float a0 = 0.f, a1 = 0.f, a2 = 0.f, a3 = 0.f;
        #pragma unroll
        for (int t = 0; t < 16; ++t) {
            float4 kb = *(const float4*)(kr + (t << 2));  // scalar/broadcast load
            a0 += fabsf(qreg[4 * t + 0] - kb.x);
            a1 += fabsf(qreg[4 * t + 1] - kb.y);
            a2 += fabsf(qreg[4 * t + 2] - kb.z);
            a3 += fabsf(qreg[4 * t + 3] - kb.w);
        }
        float madd = (1.0f - mask[j0 + jb + jj]) * 1e6f;
        float zpv = fmaxf((a0 + a1 + a2 + a3) * sc - al, 0.0f) + madd;
        zsT[jb + jj][lane] = zpv;
        zsum += zpv;
    }
    partial[w][lane] = zsum;
    __syncthreads();

    if (u < 64) {
        float zs8 = 0.f;
        #pragma unroll
        for (int p = 0; p < 8; ++p) zs8 += partial[p][u];
        Zpart[((h << 9) + i0 + u) * 16 + jt] = zs8;
    }

    // transposed, coalesced zp write: thread -> row il, 4 consecutive j
    {
        int il = u >> 3;               // 0..63
        int jg = (u & 7) << 2;         // 0..28
        float4 o;
        o.x = zsT[jg + 0][il];
        o.y = zsT[jg + 1][il];
        o.z = zsT[jg + 2][il];
        o.w = zsT[jg + 3][il];
        *(float4*)(zp + ((h << 9) + i0 + il) * S + j0 + jg) = o;
    }
}

// ---------------- ctx: ctx[i][d] = sum_j max(v,z') - Zsum, bf16 out ----------------
__global__ __launch_bounds__(512) void ctx_kernel(
    const float* __restrict__ V, const float* __restrict__ zp,
    const float* __restrict__ Zpart, __bf16* __restrict__ ctxb)
{
    int blk = blockIdx.x;
    int h = blk >> 6;
    int it = blk & 63;
    int i0 = it << 3;
    int c0 = h << 6;
    int u = threadIdx.x;
    int w = u >> 6, lane = u & 63;

    __shared__ float part[8][8][64];

    int wu = __builtin_amdgcn_readfirstlane(w);
    float acc[8] = {};

    #pragma unroll
    for (int cch = 0; cch < 4; ++cch) {
        int jg = (cch << 7) + (wu << 4);                  // uniform
        float vv[16];
        #pragma unroll
        for (int t = 0; t < 16; ++t)
            vv[t] = V[(jg + t) * Dm + c0 + lane];         // coalesced b32

        const float* zbase = zp + ((h * S) + i0) * S + jg; // uniform pointer
        #pragma unroll
        for (int ii = 0; ii < 8; ++ii) {
            const float* zrow = zbase + ii * S;
            #pragma unroll
            for (int q4 = 0; q4 < 4; ++q4) {
                float4 z4 = *(const float4*)(zrow + (q4 << 2));  // scalar/broadcast
                float t0 = fmaxf(vv[(q4 << 2) + 0], z4.x) + fmaxf(vv[(q4 << 2) + 1], z4.y);
                float t1 = fmaxf(vv[(q4 << 2) + 2], z4.z) + fmaxf(vv[(q4 << 2) + 3], z4.w);
                acc[ii] += t0 + t1;
            }
        }
    }

    #pragma unroll
    for (int ii = 0; ii < 8; ++ii) part[w][ii][lane] = acc[ii];
    __syncthreads();
    {
        int ii = u >> 6;
        float s = 0.f;
        #pragma unroll
        for (int ww = 0; ww < 8; ++ww) s += part[ww][ii][lane];
        float zsum = 0.f;
        const float* zpr = Zpart + ((h * S) + (i0 + ii)) * 16;
        #pragma unroll
        for (int p = 0; p < 16; ++p) zsum += zpr[p];
        ctxb[(i0 + ii) * Dm + c0 + lane] = (__bf16)(s - zsum);
    }
}

extern "C" void kernel_launch(void* const* d_in, const int* in_sizes, int n_in,
                              void* d_out, int out_size, void* d_ws, size_t ws_size,
                              hipStream_t stream) {
    const float* hs    = (const float*)d_in[0];
    const float* mask  = (const float*)d_in[1];
    const float* Wq    = (const float*)d_in[2];
    const float* bq    = (const float*)d_in[3];
    const float* Wk    = (const float*)d_in[4];
    const float* bk    = (const float*)d_in[5];
    const float* Wv    = (const float*)d_in[6];
    const float* bv    = (const float*)d_in[7];
    const float* Wo    = (const float*)d_in[8];
    const float* bo    = (const float*)d_in[9];
    const float* gamma = (const float*)d_in[10];
    const float* alpha = (const float*)d_in[11];
    float* out = (float*)d_out;

    char* base = (char*)d_ws;
    float*  zp    = (float*)(base);                               // 8 MB
    float*  Zpart = (float*)(base + (8u << 20));                  // 256 KB
    float*  Qb    = (float*)(base + (8u << 20) + (256u << 10));   // 1 MB
    float*  Kb    = Qb + S * Dm;                                  // 1 MB
    float*  Vb    = Kb + S * Dm;                                  // 1 MB
    __bf16* Abf   = (__bf16*)(Vb + S * Dm);                       // 0.5 MB
    __bf16* T0    = Abf + S * Dm;                                 // 0.5 MB each
    __bf16* T1    = T0 + S * Dm;
    __bf16* T2    = T1 + S * Dm;
    __bf16* T3    = T2 + S * Dm;
    __bf16* Cbf   = T3 + S * Dm;

    hipLaunchKernelGGL(prep_kernel, dim3(384), dim3(256), 0, stream,
                       hs, Wq, Wk, Wv, Wo, Abf, T0, T1, T2, T3);
    hipLaunchKernelGGL(mfma_gemm3, dim3(768), dim3(256), 0, stream,
                       Abf, T0, T1, T2, bq, bk, bv, Qb, Kb, Vb);
    hipLaunchKernelGGL(zfast_kernel, dim3(1024), dim3(512), 0, stream,
                       Qb, Kb, mask, gamma, alpha, zp, Zpart);
    hipLaunchKernelGGL(ctx_kernel, dim3(512), dim3(512), 0, stream,
                       Vb, zp, Zpart, Cbf);
    hipLaunchKernelGGL(mfma_gemm3, dim3(256), dim3(256), 0, stream,
                       Cbf, T3, T3, T3, bo, bo, bo, out, out, out);
}

// Round 8
// 61.410 us; speedup vs baseline: 1.1165x; 1.1165x over previous
//
#include <hip/hip_runtime.h>

#define S 512
#define Dm 512

typedef __bf16 bf16x8 __attribute__((ext_vector_type(8)));
typedef float f32x4 __attribute__((ext_vector_type(4)));

// ---------------- bf16 MFMA GEMM with inline fp32->bf16 conversion ----------------
// O = A*W + bias. W fp32 [K][N] read strided (lane-coalesced) + cvt.
// A: fp32 [S][Dm] (A_BF16=false) or bf16 [S][Dm] (A_BF16=true).
// 32x32 tile, 256 thr = 2x2 waves of one 16x16 MFMA each.
template<bool A_BF16>
__global__ __launch_bounds__(256) void gemm_icvt(
    const void* __restrict__ Aptr,
    const float* __restrict__ W0, const float* __restrict__ W1, const float* __restrict__ W2,
    const float* __restrict__ b0, const float* __restrict__ b1, const float* __restrict__ b2,
    float* __restrict__ O0, float* __restrict__ O1, float* __restrict__ O2)
{
    int blk = blockIdx.x;
    int m = blk >> 8;
    int tile = blk & 255;
    const float* W = (m == 0) ? W0 : (m == 1) ? W1 : W2;
    const float* bias = (m == 0) ? b0 : (m == 1) ? b1 : b2;
    float* O = (m == 0) ? O0 : (m == 1) ? O1 : O2;
    int rt = tile >> 4, ct = tile & 15;

    int u = threadIdx.x;
    int w = u >> 6, lane = u & 63;
    int r = lane & 15, kg = lane >> 4;

    int row0 = (rt << 5) + ((w >> 1) << 4);
    int col0 = (ct << 5) + ((w & 1) << 4);

    // B: W[k][col0+r] for k = k0 + kg*8 + t
    const float* Bp = W + (kg << 3) * Dm + col0 + r;

    f32x4 acc = {0.f, 0.f, 0.f, 0.f};

    #pragma unroll 4
    for (int k0 = 0; k0 < Dm; k0 += 32) {
        bf16x8 a;
        if constexpr (A_BF16) {
            const __bf16* Ab = (const __bf16*)Aptr;
            a = *(const bf16x8*)(Ab + (row0 + r) * Dm + k0 + (kg << 3));
        } else {
            const float* Af = (const float*)Aptr;
            float4 a0 = *(const float4*)(Af + (row0 + r) * Dm + k0 + (kg << 3));
            float4 a1 = *(const float4*)(Af + (row0 + r) * Dm + k0 + (kg << 3) + 4);
            a[0] = (__bf16)a0.x; a[1] = (__bf16)a0.y; a[2] = (__bf16)a0.z; a[3] = (__bf16)a0.w;
            a[4] = (__bf16)a1.x; a[5] = (__bf16)a1.y; a[6] = (__bf16)a1.z; a[7] = (__bf16)a1.w;
        }
        bf16x8 b;
        #pragma unroll
        for (int t = 0; t < 8; ++t)
            b[t] = (__bf16)Bp[(k0 + t) * Dm];
        acc = __builtin_amdgcn_mfma_f32_16x16x32_bf16(a, b, acc, 0, 0, 0);
    }

    int orow = row0 + (kg << 2);
    float bb = bias[col0 + r];
    #pragma unroll
    for (int t = 0; t < 4; ++t)
        O[(orow + t) * Dm + col0 + r] = acc[t] + bb;
}

// ---------------- z-pass: lane = i, Q-row in VGPRs, K via wave-uniform loads ----------------
// grid 512 = 8 heads * 8 i-tiles(64) * 8 j-tiles(64). 512 thr = 8 waves; wave w: 8 j's.
__global__ __launch_bounds__(512) void zfast_kernel(
    const float* __restrict__ Q, const float* __restrict__ K,
    const float* __restrict__ mask, const float* __restrict__ gamma,
    const float* __restrict__ alpha,
    float* __restrict__ zp, float* __restrict__ Zpart)
{
    int blk = blockIdx.x;
    int h  = blk >> 6;
    int it = (blk >> 3) & 7;
    int jt = blk & 7;
    int i0 = it << 6;
    int j0 = jt << 6;
    int c0 = h << 6;

    int u = threadIdx.x;
    int w = u >> 6, lane = u & 63;

    __shared__ float zsT[64][65];      // [j][i] transpose buffer
    __shared__ float partial[8][64];

    float qreg[64];
    #pragma unroll
    for (int t = 0; t < 16; ++t) {
        float4 qv = *(const float4*)(Q + (i0 + lane) * Dm + c0 + (t << 2));
        qreg[4 * t + 0] = qv.x; qreg[4 * t + 1] = qv.y;
        qreg[4 * t + 2] = qv.z; qreg[4 * t + 3] = qv.w;
    }

    float sc = 1.0f / (gamma[0] * 8.0f);
    float al = alpha[0];

    int jb = __builtin_amdgcn_readfirstlane(w << 3);

    float zsum = 0.f;
    #pragma unroll 2
    for (int jj = 0; jj < 8; ++jj) {
        const float* kr = K + (j0 + jb + jj) * Dm + c0;   // uniform pointer
        float a0 = 0.f, a1 = 0.f, a2 = 0.f, a3 = 0.f;
        #pragma unroll
        for (int t = 0; t < 16; ++t) {
            float4 kb = *(const float4*)(kr + (t << 2));  // scalar/broadcast load
            a0 += fabsf(qreg[4 * t + 0] - kb.x);
            a1 += fabsf(qreg[4 * t + 1] - kb.y);
            a2 += fabsf(qreg[4 * t + 2] - kb.z);
            a3 += fabsf(qreg[4 * t + 3] - kb.w);
        }
        float madd = (1.0f - mask[j0 + jb + jj]) * 1e6f;
        float zpv = fmaxf((a0 + a1 + a2 + a3) * sc - al, 0.0f) + madd;
        zsT[jb + jj][lane] = zpv;
        zsum += zpv;
    }
    partial[w][lane] = zsum;
    __syncthreads();

    if (u < 64) {
        float zs8 = 0.f;
        #pragma unroll
        for (int p = 0; p < 8; ++p) zs8 += partial[p][u];
        Zpart[((h << 9) + i0 + u) * 8 + jt] = zs8;
    }

    {
        int il = u >> 3;
        int jg = (u & 7) << 3;
        float* orow = zp + ((h << 9) + i0 + il) * S + j0 + jg;
        #pragma unroll
        for (int q4 = 0; q4 < 2; ++q4) {
            float4 o;
            o.x = zsT[jg + (q4 << 2) + 0][il];
            o.y = zsT[jg + (q4 << 2) + 1][il];
            o.z = zsT[jg + (q4 << 2) + 2][il];
            o.w = zsT[jg + (q4 << 2) + 3][il];
            *(float4*)(orow + (q4 << 2)) = o;
        }
    }
}

// ---------------- ctx: ctx[i][d] = sum_j max(v,z') - Zsum, bf16 out ----------------
// grid 512 = 8 heads * 64 i-tiles(8). 512 thr = 8 waves; lane = d.
// 4 sub-accumulators per row -> 2 VALU ops per element exactly.
__global__ __launch_bounds__(512) void ctx_kernel(
    const float* __restrict__ V, const float* __restrict__ zp,
    const float* __restrict__ Zpart, __bf16* __restrict__ ctxb)
{
    int blk = blockIdx.x;
    int h = blk >> 6;
    int it = blk & 63;
    int i0 = it << 3;
    int c0 = h << 6;
    int u = threadIdx.x;
    int w = u >> 6, lane = u & 63;

    __shared__ float part[8][8][64];

    int wu = __builtin_amdgcn_readfirstlane(w);
    float acc[8][4] = {};

    #pragma unroll
    for (int cch = 0; cch < 4; ++cch) {
        int jg = (cch << 7) + (wu << 4);                  // uniform
        float vv[16];
        #pragma unroll
        for (int t = 0; t < 16; ++t)
            vv[t] = V[(jg + t) * Dm + c0 + lane];         // coalesced b32

        const float* zbase = zp + ((h * S) + i0) * S + jg; // uniform pointer
        #pragma unroll
        for (int ii = 0; ii < 8; ++ii) {
            const float* zrow = zbase + ii * S;
            #pragma unroll
            for (int q4 = 0; q4 < 4; ++q4) {
                float4 z4 = *(const float4*)(zrow + (q4 << 2));  // scalar/broadcast
                acc[ii][0] += fmaxf(vv[(q4 << 2) + 0], z4.x);
                acc[ii][1] += fmaxf(vv[(q4 << 2) + 1], z4.y);
                acc[ii][2] += fmaxf(vv[(q4 << 2) + 2], z4.z);
                acc[ii][3] += fmaxf(vv[(q4 << 2) + 3], z4.w);
            }
        }
    }

    #pragma unroll
    for (int ii = 0; ii < 8; ++ii)
        part[w][ii][lane] = (acc[ii][0] + acc[ii][1]) + (acc[ii][2] + acc[ii][3]);
    __syncthreads();
    {
        int ii = u >> 6;
        float s = 0.f;
        #pragma unroll
        for (int ww = 0; ww < 8; ++ww) s += part[ww][ii][lane];
        float zsum = 0.f;
        const float* zpr = Zpart + ((h * S) + (i0 + ii)) * 8;
        #pragma unroll
        for (int p = 0; p < 8; ++p) zsum += zpr[p];
        ctxb[(i0 + ii) * Dm + c0 + lane] = (__bf16)(s - zsum);
    }
}

extern "C" void kernel_launch(void* const* d_in, const int* in_sizes, int n_in,
                              void* d_out, int out_size, void* d_ws, size_t ws_size,
                              hipStream_t stream) {
    const float* hs    = (const float*)d_in[0];
    const float* mask  = (const float*)d_in[1];
    const float* Wq    = (const float*)d_in[2];
    const float* bq    = (const float*)d_in[3];
    const float* Wk    = (const float*)d_in[4];
    const float* bk    = (const float*)d_in[5];
    const float* Wv    = (const float*)d_in[6];
    const float* bv    = (const float*)d_in[7];
    const float* Wo    = (const float*)d_in[8];
    const float* bo    = (const float*)d_in[9];
    const float* gamma = (const float*)d_in[10];
    const float* alpha = (const float*)d_in[11];
    float* out = (float*)d_out;

    char* base = (char*)d_ws;
    float*  zp    = (float*)(base);                               // 8 MB
    float*  Zpart = (float*)(base + (8u << 20));                  // 128 KB
    float*  Qb    = (float*)(base + (8u << 20) + (128u << 10));   // 1 MB
    float*  Kb    = Qb + S * Dm;                                  // 1 MB
    float*  Vb    = Kb + S * Dm;                                  // 1 MB
    __bf16* Cbf   = (__bf16*)(Vb + S * Dm);                       // 0.5 MB

    hipLaunchKernelGGL((gemm_icvt<false>), dim3(768), dim3(256), 0, stream,
                       (const void*)hs, Wq, Wk, Wv, bq, bk, bv, Qb, Kb, Vb);
    hipLaunchKernelGGL(zfast_kernel, dim3(512), dim3(512), 0, stream,
                       Qb, Kb, mask, gamma, alpha, zp, Zpart);
    hipLaunchKernelGGL(ctx_kernel, dim3(512), dim3(512), 0, stream,
                       Vb, zp, Zpart, Cbf);
    hipLaunchKernelGGL((gemm_icvt<true>), dim3(256), dim3(256), 0, stream,
                       (const void*)Cbf, Wo, Wo, Wo, bo, bo, bo, out, out, out);
}